// Round 1
// baseline (91.658 us; speedup 1.0000x reference)
//
#include <hip/hip_runtime.h>

#define BN   8192
#define DIM  128
#define NCLS 128

typedef __attribute__((ext_vector_type(8))) short bf16x8;   // 8 x bf16 = 4 VGPRs
typedef __attribute__((ext_vector_type(4))) float f32x4;

// round-to-nearest-even f32 -> bf16
static __device__ __forceinline__ unsigned short f2bf(float x) {
    union { float f; unsigned u; } c; c.f = x;
    unsigned r = c.u + 0x7FFFu + ((c.u >> 16) & 1u);
    return (unsigned short)(r >> 16);
}

static __device__ __forceinline__ bf16x8 ldb8(const unsigned short* p) {
    return *reinterpret_cast<const bf16x8*>(p);
}

// ---------------------------------------------------------------- init
__global__ __launch_bounds__(256) void init_kernel(unsigned* __restrict__ hp2,
                                                   unsigned* __restrict__ hn2,
                                                   int* __restrict__ hist) {
    int i = blockIdx.x * 256 + threadIdx.x;          // grid covers exactly BN
    hp2[i] = 0u;                                     // biased d2+1 = 0 -> d2 = -1 -> relu -> 0
    hn2[i] = 0x7F7FFFFFu;                            // FLT_MAX bits
    if (i < NCLS) hist[i] = 0;
}

// ------------------------------------------------------ normalize + hist
// one wave per row: lane holds 2 consecutive floats
__global__ __launch_bounds__(256) void normalize_kernel(const float* __restrict__ emb,
                                                        const int* __restrict__ labels,
                                                        unsigned short* __restrict__ ebf,
                                                        float* __restrict__ sq,
                                                        int* __restrict__ hist) {
    int row  = blockIdx.x * 4 + (threadIdx.x >> 6);
    int lane = threadIdx.x & 63;
    float2 v = reinterpret_cast<const float2*>(emb + row * DIM)[lane];
    float ss = v.x * v.x + v.y * v.y;
#pragma unroll
    for (int m = 1; m < 64; m <<= 1) ss += __shfl_xor(ss, m);
    float norm = fmaxf(sqrtf(ss), 1e-12f);
    float nx = v.x / norm, ny = v.y / norm;
    // sq = diag of Gram on the normalized fp32 values (faithful to reference)
    float s2 = nx * nx + ny * ny;
#pragma unroll
    for (int m = 1; m < 64; m <<= 1) s2 += __shfl_xor(s2, m);
    ushort2 bv; bv.x = f2bf(nx); bv.y = f2bf(ny);
    reinterpret_cast<ushort2*>(ebf + row * DIM)[lane] = bv;
    if (lane == 0) {
        sq[row] = s2;
        atomicAdd(&hist[labels[row]], 1);
    }
}

// ---------------------------------------------------------------- main
// 512 blocks = 128 i-tiles (64 rows) x 4 j-splits. 256 thr = 4 waves.
// Each wave: A panel (4 x 16-row subtiles, K=128) in registers, sweeps 512 j.
// Tracks biased d2+1 (always > 0) so uint-bits atomicMax/Min are order-safe.
__global__ __launch_bounds__(256) void tri_main(const unsigned short* __restrict__ ebf,
                                                const float* __restrict__ sq,
                                                const int* __restrict__ labels,
                                                unsigned* __restrict__ hp2,
                                                unsigned* __restrict__ hn2) {
    const int tid  = threadIdx.x;
    const int wave = tid >> 6;
    const int lane = tid & 63;
    const int lr   = lane & 15;        // A row / B col / C col within tile
    const int lk   = lane >> 4;        // k-group
    const int itile  = blockIdx.x >> 2;
    const int jsplit = blockIdx.x & 3;
    const int i0 = itile * 64;

    // preload A fragments: 4 subtiles x 4 k-steps (identical pattern for A and B frags)
    bf16x8 a[4][4];
#pragma unroll
    for (int t = 0; t < 4; ++t) {
        const unsigned short* ar = ebf + (i0 + t * 16 + lr) * DIM + lk * 8;
#pragma unroll
        for (int kk = 0; kk < 4; ++kk) a[t][kk] = ldb8(ar + kk * 32);
    }

    // per-accum-row constants: row = i0 + t*16 + lk*4 + m
    float sqi1[4][4];
    int   labi[4][4];
#pragma unroll
    for (int t = 0; t < 4; ++t)
#pragma unroll
        for (int m = 0; m < 4; ++m) {
            int r = i0 + t * 16 + lk * 4 + m;
            sqi1[t][m] = sq[r] + 1.0f;     // +1 bias folded in
            labi[t][m] = labels[r];
        }

    float hp[4][4], hn[4][4];
#pragma unroll
    for (int t = 0; t < 4; ++t)
#pragma unroll
        for (int m = 0; m < 4; ++m) { hp[t][m] = 0.0f; hn[t][m] = 3.402823466e38f; }

    const int jbase = jsplit * 2048 + wave * 512;
    for (int jt = 0; jt < 32; ++jt) {
        const int j0 = jbase + jt * 16;
        const int jc = j0 + lr;                        // this lane's B row == its C col
        const unsigned short* br = ebf + jc * DIM + lk * 8;
        bf16x8 b0 = ldb8(br);
        bf16x8 b1 = ldb8(br + 32);
        bf16x8 b2 = ldb8(br + 64);
        bf16x8 b3 = ldb8(br + 96);
        float sqj = sq[jc];
        int   labj = labels[jc];
#pragma unroll
        for (int t = 0; t < 4; ++t) {
            f32x4 acc = {0.f, 0.f, 0.f, 0.f};
            acc = __builtin_amdgcn_mfma_f32_16x16x32_bf16(a[t][0], b0, acc, 0, 0, 0);
            acc = __builtin_amdgcn_mfma_f32_16x16x32_bf16(a[t][1], b1, acc, 0, 0, 0);
            acc = __builtin_amdgcn_mfma_f32_16x16x32_bf16(a[t][2], b2, acc, 0, 0, 0);
            acc = __builtin_amdgcn_mfma_f32_16x16x32_bf16(a[t][3], b3, acc, 0, 0, 0);
#pragma unroll
            for (int m = 0; m < 4; ++m) {
                int  rowg = i0 + t * 16 + lk * 4 + m;
                float d2b = fmaf(-2.0f, acc[m], sqi1[t][m] + sqj);   // d2 + 1 (> 0)
                bool same = (labi[t][m] == labj);
                bool pos  = same && (rowg != jc);
                hp[t][m] = pos  ? fmaxf(hp[t][m], d2b) : hp[t][m];
                hn[t][m] = same ? hn[t][m] : fminf(hn[t][m], d2b);
            }
        }
    }

    // reduce across the 16 lanes sharing the same accum rows, then bits-atomics
#pragma unroll
    for (int t = 0; t < 4; ++t)
#pragma unroll
        for (int m = 0; m < 4; ++m) {
            float p = hp[t][m], n = hn[t][m];
#pragma unroll
            for (int s = 1; s < 16; s <<= 1) {
                p = fmaxf(p, __shfl_xor(p, s));
                n = fminf(n, __shfl_xor(n, s));
            }
            if (lr == 0) {
                int rowg = i0 + t * 16 + lk * 4 + m;
                atomicMax(&hp2[rowg], __float_as_uint(p));
                atomicMin(&hn2[rowg], __float_as_uint(n));
            }
        }
}

// ---------------------------------------------------------------- finalize
__global__ __launch_bounds__(256) void finalize_kernel(const unsigned* __restrict__ hp2,
                                                       const unsigned* __restrict__ hn2,
                                                       const int* __restrict__ labels,
                                                       const int* __restrict__ hist,
                                                       float* __restrict__ out) {
    int tid = threadIdx.x;
    float sum = 0.f, cnt = 0.f;
    for (int i = tid; i < BN; i += 256) {
        int c = hist[labels[i]];
        if (c >= 2 && c < BN) {                       // pos_any && neg_any
            float hpd2 = __uint_as_float(hp2[i]) - 1.0f;
            float hnd2 = __uint_as_float(hn2[i]) - 1.0f;
            float hpv = sqrtf(fmaxf(hpd2, 0.f));
            float hnv = sqrtf(fmaxf(hnd2, 0.f));
            // relu(hp - hn + 0.5*(1+hp)) = relu(1.5*hp - hn + 0.5)
            sum += fmaxf(1.5f * hpv - hnv + 0.5f, 0.f);
            cnt += 1.f;
        }
    }
    __shared__ float ssum[256], scnt[256];
    ssum[tid] = sum; scnt[tid] = cnt;
    __syncthreads();
    for (int s = 128; s > 0; s >>= 1) {
        if (tid < s) { ssum[tid] += ssum[tid + s]; scnt[tid] += scnt[tid + s]; }
        __syncthreads();
    }
    if (tid == 0) out[0] = ssum[0] / fmaxf(scnt[0], 1.0f);
}

// ---------------------------------------------------------------- launch
extern "C" void kernel_launch(void* const* d_in, const int* in_sizes, int n_in,
                              void* d_out, int out_size, void* d_ws, size_t ws_size,
                              hipStream_t stream) {
    const float* emb    = (const float*)d_in[0];
    const int*   labels = (const int*)d_in[1];
    float* out = (float*)d_out;

    char* ws = (char*)d_ws;
    unsigned short* ebf = (unsigned short*)ws;                    // 2 MiB  bf16 normalized E
    float*    sq   = (float*)   (ws + 2u * 1024u * 1024u);        // 32 KiB
    unsigned* hp2  = (unsigned*)(ws + 2u * 1024u * 1024u + 32u * 1024u);
    unsigned* hn2  = (unsigned*)(ws + 2u * 1024u * 1024u + 64u * 1024u);
    int*      hist = (int*)     (ws + 2u * 1024u * 1024u + 96u * 1024u);

    hipLaunchKernelGGL(init_kernel,      dim3(BN / 256), dim3(256), 0, stream, hp2, hn2, hist);
    hipLaunchKernelGGL(normalize_kernel, dim3(BN / 4),   dim3(256), 0, stream, emb, labels, ebf, sq, hist);
    hipLaunchKernelGGL(tri_main,         dim3(512),      dim3(256), 0, stream, ebf, sq, labels, hp2, hn2);
    hipLaunchKernelGGL(finalize_kernel,  dim3(1),        dim3(256), 0, stream, hp2, hn2, labels, hist, out);
}